// Round 1
// baseline (2304.760 us; speedup 1.0000x reference)
//
#include <hip/hip_runtime.h>
#include <float.h>

// Problem constants
#define NP   16384    // B*H*W pixels
#define NE   8192     // codebook entries
#define KD   256      // channels / dot length
#define HW   1024     // H*W
#define BCHW 262144   // C*H*W per batch

// ---------------------------------------------------------------------------
// Kernel A: e2[n] = sum_k codebook[n][k]^2   (one wave per codebook row)
// ---------------------------------------------------------------------------
__global__ void vq_e2_kernel(const float* __restrict__ cb, float* __restrict__ e2) {
    const int wid  = (blockIdx.x * 256 + threadIdx.x) >> 6;   // wave id = row
    const int lane = threadIdx.x & 63;
    if (wid >= NE) return;
    const float4 v = *reinterpret_cast<const float4*>(cb + wid * KD + lane * 4);
    float s = v.x * v.x + v.y * v.y + v.z * v.z + v.w * v.w;
    #pragma unroll
    for (int m = 1; m < 64; m <<= 1) s += __shfl_xor(s, m);
    if (lane == 0) e2[wid] = s;
}

// ---------------------------------------------------------------------------
// Kernel B: fused distance + argmin.
//   grid 256 wgs x 256 threads. BM=64 pixels/wg, BN=64 codes/tile, BK=64.
//   Each thread: 4 pixels x 4 codes register tile.
//   d(p,n) = e2[n] - 2*<z_p, e_n>; running (min, argmin) per pixel.
//   Index written as FLOAT values (harness reads whole d_out as f32).
// ---------------------------------------------------------------------------
__global__ __launch_bounds__(256, 4) void vq_argmin_kernel(
    const float* __restrict__ z, const float* __restrict__ cb,
    const float* __restrict__ e2, float* __restrict__ idx_out)
{
    // zs[k][p]: z is channel-first => K-major in memory: coalesced, conflict-free fill
    __shared__ float zs[64][64];
    // bs[k][n]: stride 68 floats => float4 reads 16B-aligned, 2-way conflicts (free)
    __shared__ float bs[64][68];

    const int tid = threadIdx.x;
    const int tx  = tid & 15;        // code group   (4 codes)
    const int ty  = tid >> 4;        // pixel group  (4 pixels)
    const int p0  = blockIdx.x * 64; // 64 pixels per wg, always within one batch
    const int bb  = p0 >> 10;
    const int hw0 = p0 & 1023;
    const float* zbase = z + bb * BCHW + hw0;

    float bestd[4];
    int   besti[4];
    #pragma unroll
    for (int i = 0; i < 4; ++i) { bestd[i] = FLT_MAX; besti[i] = 0; }

    for (int bt = 0; bt < NE / 64; ++bt) {
        const int n0 = bt * 64;
        float acc[4][4] = {};

        #pragma unroll 1
        for (int kc = 0; kc < 4; ++kc) {
            const int k0 = kc * 64;
            __syncthreads();
            // ---- fill zs[kk][p] : global coalesced (z already K-major) ----
            {
                const int pr = (tid & 15) * 4;   // pixel quad within row
                const int kr = tid >> 4;         // 16 k-rows per pass
                #pragma unroll
                for (int r = 0; r < 4; ++r) {
                    const int kk = kr + 16 * r;
                    *reinterpret_cast<float4*>(&zs[kk][pr]) =
                        *reinterpret_cast<const float4*>(zbase + (k0 + kk) * HW + pr);
                }
            }
            // ---- fill bs[kk][n] (transpose): conflict-free LDS stores ----
            {
                const int n  = tid & 63;          // each wave covers all 64 rows
                const int kq = (tid >> 6) * 16;   // wave's k-offset: 0,16,32,48
                #pragma unroll
                for (int q = 0; q < 4; ++q) {
                    const float4 v = *reinterpret_cast<const float4*>(
                        cb + (size_t)(n0 + n) * KD + k0 + kq + q * 4);
                    bs[kq + q * 4 + 0][n] = v.x;
                    bs[kq + q * 4 + 1][n] = v.y;
                    bs[kq + q * 4 + 2][n] = v.z;
                    bs[kq + q * 4 + 3][n] = v.w;
                }
            }
            __syncthreads();
            // ---- 4x4 register-tile FMA over BK=64 ----
            #pragma unroll 16
            for (int kk = 0; kk < 64; ++kk) {
                const float4 az = *reinterpret_cast<const float4*>(&zs[kk][ty * 4]);
                const float4 bz = *reinterpret_cast<const float4*>(&bs[kk][tx * 4]);
                const float a[4] = {az.x, az.y, az.z, az.w};
                const float b[4] = {bz.x, bz.y, bz.z, bz.w};
                #pragma unroll
                for (int i = 0; i < 4; ++i)
                    #pragma unroll
                    for (int j = 0; j < 4; ++j)
                        acc[i][j] += a[i] * b[j];
            }
        }

        // ---- distances + running argmin (ascending code order => first-hit tiebreak) ----
        #pragma unroll
        for (int j = 0; j < 4; ++j) {
            const int   n   = n0 + tx * 4 + j;
            const float e2n = e2[n];
            #pragma unroll
            for (int i = 0; i < 4; ++i) {
                const float d = e2n - 2.0f * acc[i][j];
                if (d < bestd[i]) { bestd[i] = d; besti[i] = n; }
            }
        }
    }

    // ---- reduce across the 16 tx-lanes (same ty) with smaller-index tiebreak ----
    #pragma unroll
    for (int i = 0; i < 4; ++i) {
        float d  = bestd[i];
        int   bi = besti[i];
        #pragma unroll
        for (int m = 1; m < 16; m <<= 1) {
            const float od = __shfl_xor(d, m);
            const int   oi = __shfl_xor(bi, m);
            if (od < d || (od == d && oi < bi)) { d = od; bi = oi; }
        }
        if (tx == 0) idx_out[p0 + ty * 4 + i] = (float)bi;
    }
}

// ---------------------------------------------------------------------------
// Kernel C: z_q gather (channel-first) + loss = 1.25*mean((z_q - z)^2)
// ---------------------------------------------------------------------------
__global__ void vq_out_kernel(const float* __restrict__ z, const float* __restrict__ cb,
                              const float* __restrict__ idxf, float* __restrict__ out,
                              float* __restrict__ loss)
{
    const int e  = (blockIdx.x * 256 + threadIdx.x) * 4;
    const int bb = e >> 18;
    const int c  = (e >> 10) & 255;
    const int hw = e & 1023;
    const int p  = bb * HW + hw;

    const float4 zv = *reinterpret_cast<const float4*>(z + e);
    const float zl[4] = {zv.x, zv.y, zv.z, zv.w};
    float o[4];
    float ls = 0.f;
    #pragma unroll
    for (int i = 0; i < 4; ++i) {
        const int n = (int)idxf[p + i];
        o[i] = cb[(size_t)n * KD + c];
        const float dd = o[i] - zl[i];
        ls += dd * dd;
    }
    const float4 ov = {o[0], o[1], o[2], o[3]};
    *reinterpret_cast<float4*>(out + e) = ov;

    #pragma unroll
    for (int m = 1; m < 64; m <<= 1) ls += __shfl_xor(ls, m);
    if ((threadIdx.x & 63) == 0) atomicAdd(loss, ls * (1.25f / 4194304.f));
}

// ---------------------------------------------------------------------------
extern "C" void kernel_launch(void* const* d_in, const int* in_sizes, int n_in,
                              void* d_out, int out_size, void* d_ws, size_t ws_size,
                              hipStream_t stream) {
    const float* z  = (const float*)d_in[0];
    const float* cb = (const float*)d_in[1];
    float* out  = (float*)d_out;            // [0 .. 4194303]  z_q channel-first
    float* idxf = out + 4194304;            // [.. 4210687]    index as float
    float* loss = out + 4210688;            // [4210688]       loss scalar
    float* e2   = (float*)d_ws;             // 8192 floats scratch

    hipMemsetAsync(loss, 0, sizeof(float), stream);
    vq_e2_kernel<<<NE / 4, 256, 0, stream>>>(cb, e2);
    vq_argmin_kernel<<<NP / 64, 256, 0, stream>>>(z, cb, e2, idxf);
    vq_out_kernel<<<4194304 / 1024, 256, 0, stream>>>(z, cb, idxf, out, loss);
}

// Round 2
// 1059.159 us; speedup vs baseline: 2.1760x; 2.1760x over previous
//
#include <hip/hip_runtime.h>
#include <float.h>

// Problem constants
#define NP   16384    // B*H*W pixels
#define NE   8192     // codebook entries
#define KD   256      // channels / dot length
#define HW   1024     // H*W
#define BCHW 262144   // C*H*W per batch

// Tiling
#define BM 128        // pixels per wg
#define BN 128        // codes per tile
#define BK 32         // k per stage
#define NSPLIT 8      // codebook split across wgs -> grid = 128*8 = 1024

// ---------------------------------------------------------------------------
// Kernel A: e2[n] = sum_k codebook[n][k]^2   (one wave per codebook row)
// ---------------------------------------------------------------------------
__global__ void vq_e2_kernel(const float* __restrict__ cb, float* __restrict__ e2) {
    const int wid  = (blockIdx.x * 256 + threadIdx.x) >> 6;
    const int lane = threadIdx.x & 63;
    if (wid >= NE) return;
    const float4 v = *reinterpret_cast<const float4*>(cb + wid * KD + lane * 4);
    float s = v.x * v.x + v.y * v.y + v.z * v.z + v.w * v.w;
    #pragma unroll
    for (int m = 1; m < 64; m <<= 1) s += __shfl_xor(s, m);
    if (lane == 0) e2[wid] = s;
}

// float -> order-preserving uint key (no NaNs in this data)
__device__ __forceinline__ unsigned int fkey(float f) {
    unsigned int u = __float_as_uint(f);
    return u ^ ((u >> 31) ? 0xFFFFFFFFu : 0x80000000u);
}

// ---------------------------------------------------------------------------
// Kernel B: fused distance + argmin, 128x128 tile, 8x8 per thread, split-N=8.
//   Per-wg best folded via shfl, combined across wgs with atomicMin on
//   packed (dist_key<<32 | idx)  -> ties pick smaller idx (numpy semantics).
// ---------------------------------------------------------------------------
__global__ __launch_bounds__(256, 4) void vq_argmin_kernel(
    const float* __restrict__ z, const float* __restrict__ cb,
    const float* __restrict__ e2, unsigned long long* __restrict__ best)
{
    __shared__ float zs[BK][BM];       // 16 KB, z K-major: coalesced fill
    __shared__ float bs[BK][BN + 4];   // 16.5 KB, codebook transposed on store

    const int tid = threadIdx.x;
    const int tx  = tid & 15;          // code octet
    const int ty  = tid >> 4;          // pixel octet
    const int pb  = blockIdx.x >> 3;   // pixel block
    const int s   = blockIdx.x & 7;    // codebook split
    const int p0  = pb * BM;
    const int bb  = p0 >> 10;
    const int hw0 = p0 & 1023;
    const float* zbase = z + bb * BCHW + hw0;
    const int nbase = s * (NE / NSPLIT);

    float bestd[8];
    int   besti[8];
    #pragma unroll
    for (int i = 0; i < 8; ++i) { bestd[i] = FLT_MAX; besti[i] = 0; }

    for (int bt = 0; bt < (NE / NSPLIT) / BN; ++bt) {   // 8 tiles
        const int n0 = nbase + bt * BN;
        float acc[8][8] = {};

        #pragma unroll 1
        for (int kc = 0; kc < KD / BK; ++kc) {          // 8 stages
            const int k0 = kc * BK;
            __syncthreads();
            // ---- zs[kk][p]: z channel-first => coalesced float4 ----
            {
                const int pr = (tid & 31) * 4;
                const int kr = tid >> 5;                // 0..7
                #pragma unroll
                for (int r = 0; r < 4; ++r) {
                    const int kk = kr + 8 * r;
                    *reinterpret_cast<float4*>(&zs[kk][pr]) =
                        *reinterpret_cast<const float4*>(zbase + (k0 + kk) * HW + pr);
                }
            }
            // ---- bs[kk][n]: transpose codebook rows into k-major ----
            {
                const int n  = tid & 127;
                const int kh = (tid >> 7) * 16;         // 0 or 16
                #pragma unroll
                for (int q = 0; q < 4; ++q) {
                    const float4 v = *reinterpret_cast<const float4*>(
                        cb + (size_t)(n0 + n) * KD + k0 + kh + q * 4);
                    bs[kh + q * 4 + 0][n] = v.x;
                    bs[kh + q * 4 + 1][n] = v.y;
                    bs[kh + q * 4 + 2][n] = v.z;
                    bs[kh + q * 4 + 3][n] = v.w;
                }
            }
            __syncthreads();
            // ---- 8x8 register tile over BK ----
            #pragma unroll 4
            for (int kk = 0; kk < BK; ++kk) {
                const float4 a0 = *reinterpret_cast<const float4*>(&zs[kk][ty * 8]);
                const float4 a1 = *reinterpret_cast<const float4*>(&zs[kk][ty * 8 + 4]);
                const float4 b0 = *reinterpret_cast<const float4*>(&bs[kk][tx * 8]);
                const float4 b1 = *reinterpret_cast<const float4*>(&bs[kk][tx * 8 + 4]);
                const float a[8] = {a0.x, a0.y, a0.z, a0.w, a1.x, a1.y, a1.z, a1.w};
                const float b[8] = {b0.x, b0.y, b0.z, b0.w, b1.x, b1.y, b1.z, b1.w};
                #pragma unroll
                for (int i = 0; i < 8; ++i)
                    #pragma unroll
                    for (int j = 0; j < 8; ++j)
                        acc[i][j] += a[i] * b[j];
            }
        }

        // ---- distances + running argmin (ascending n => strict < keeps first) ----
        #pragma unroll
        for (int j = 0; j < 8; ++j) {
            const int   n   = n0 + tx * 8 + j;
            const float e2n = e2[n];
            #pragma unroll
            for (int i = 0; i < 8; ++i) {
                const float d = e2n - 2.0f * acc[i][j];
                if (d < bestd[i]) { bestd[i] = d; besti[i] = n; }
            }
        }
    }

    // ---- fold across the 16 tx lanes, then one atomic per pixel ----
    #pragma unroll
    for (int i = 0; i < 8; ++i) {
        float d  = bestd[i];
        int   bi = besti[i];
        #pragma unroll
        for (int m = 1; m < 16; m <<= 1) {
            const float od = __shfl_xor(d, m);
            const int   oi = __shfl_xor(bi, m);
            if (od < d || (od == d && oi < bi)) { d = od; bi = oi; }
        }
        if (tx == 0) {
            const unsigned long long pk =
                ((unsigned long long)fkey(d) << 32) | (unsigned int)bi;
            atomicMin(&best[p0 + ty * 8 + i], pk);
        }
    }
}

// ---------------------------------------------------------------------------
// Kernel C: unpack winning index -> float into d_out
// ---------------------------------------------------------------------------
__global__ void vq_idx_kernel(const unsigned long long* __restrict__ best,
                              float* __restrict__ idxf) {
    const int p = blockIdx.x * 256 + threadIdx.x;
    idxf[p] = (float)(unsigned int)(best[p] & 0xFFFFFFFFull);
}

// ---------------------------------------------------------------------------
// Kernel D: z_q gather (channel-first) + loss = 1.25*mean((z_q - z)^2)
// ---------------------------------------------------------------------------
__global__ void vq_out_kernel(const float* __restrict__ z, const float* __restrict__ cb,
                              const float* __restrict__ idxf, float* __restrict__ out,
                              float* __restrict__ loss)
{
    const int e  = (blockIdx.x * 256 + threadIdx.x) * 4;
    const int bb = e >> 18;
    const int c  = (e >> 10) & 255;
    const int hw = e & 1023;
    const int p  = bb * HW + hw;

    const float4 zv = *reinterpret_cast<const float4*>(z + e);
    const float zl[4] = {zv.x, zv.y, zv.z, zv.w};
    float o[4];
    float ls = 0.f;
    #pragma unroll
    for (int i = 0; i < 4; ++i) {
        const int n = (int)idxf[p + i];
        o[i] = cb[(size_t)n * KD + c];
        const float dd = o[i] - zl[i];
        ls += dd * dd;
    }
    const float4 ov = {o[0], o[1], o[2], o[3]};
    *reinterpret_cast<float4*>(out + e) = ov;

    #pragma unroll
    for (int m = 1; m < 64; m <<= 1) ls += __shfl_xor(ls, m);
    if ((threadIdx.x & 63) == 0) atomicAdd(loss, ls * (1.25f / 4194304.f));
}

// ---------------------------------------------------------------------------
extern "C" void kernel_launch(void* const* d_in, const int* in_sizes, int n_in,
                              void* d_out, int out_size, void* d_ws, size_t ws_size,
                              hipStream_t stream) {
    const float* z  = (const float*)d_in[0];
    const float* cb = (const float*)d_in[1];
    float* out  = (float*)d_out;            // [0 .. 4194303]  z_q channel-first
    float* idxf = out + 4194304;            // [.. 4210687]    index as float
    float* loss = out + 4210688;            // [4210688]       loss scalar

    unsigned long long* best = (unsigned long long*)d_ws;          // 128 KB
    float* e2 = (float*)((char*)d_ws + NP * sizeof(unsigned long long));

    hipMemsetAsync(best, 0xFF, NP * sizeof(unsigned long long), stream);
    hipMemsetAsync(loss, 0, sizeof(float), stream);
    vq_e2_kernel<<<NE / 4, 256, 0, stream>>>(cb, e2);
    vq_argmin_kernel<<<(NP / BM) * NSPLIT, 256, 0, stream>>>(z, cb, e2, best);
    vq_idx_kernel<<<NP / 256, 256, 0, stream>>>(best, idxf);
    vq_out_kernel<<<4194304 / 1024, 256, 0, stream>>>(z, cb, idxf, out, loss);
}

// Round 3
// 684.842 us; speedup vs baseline: 3.3654x; 1.5466x over previous
//
#include <hip/hip_runtime.h>
#include <float.h>

#define NPIX 16384
#define NE   8192
#define KD   256
#define HW   1024
#define BCHW 262144
#define CAND_MAX 65536
#define DELTA 4e-5f

typedef __attribute__((ext_vector_type(8))) short short8;
typedef __attribute__((ext_vector_type(4))) short short4v;
typedef __attribute__((ext_vector_type(4))) float f32x4;
typedef unsigned long long u64;
typedef unsigned int u32;

__device__ __forceinline__ u32 fkey(float f) {
    u32 u = __float_as_uint(f);
    return u ^ ((u >> 31) ? 0xFFFFFFFFu : 0x80000000u);
}
__device__ __forceinline__ float unfkey(u32 k) {
    return __uint_as_float((k >> 31) ? (k ^ 0x80000000u) : ~k);
}
__device__ __forceinline__ short bf16rne(float f) {
    u32 u = __float_as_uint(f);
    u += 0x7FFFu + ((u >> 16) & 1u);
    return (short)(u >> 16);
}

#define GLDS(gp, lp) __builtin_amdgcn_global_load_lds( \
    (const __attribute__((address_space(1))) void*)(gp), \
    (__attribute__((address_space(3))) void*)(lp), 16, 0, 0)

// ---------------------------------------------------------------------------
// e2[n] = ||e_n||^2
// ---------------------------------------------------------------------------
__global__ void vq_e2_kernel(const float* __restrict__ cb, float* __restrict__ e2) {
    const int wid  = (blockIdx.x * 256 + threadIdx.x) >> 6;
    const int lane = threadIdx.x & 63;
    if (wid >= NE) return;
    const float4 v = *reinterpret_cast<const float4*>(cb + wid * KD + lane * 4);
    float s = v.x * v.x + v.y * v.y + v.z * v.z + v.w * v.w;
    #pragma unroll
    for (int m = 1; m < 64; m <<= 1) s += __shfl_xor(s, m);
    if (lane == 0) e2[wid] = s;
}

// ---------------------------------------------------------------------------
// codebook fp32 -> bf16 (row-major, same layout)
// ---------------------------------------------------------------------------
__global__ void vq_eh(const float* __restrict__ cb, short* __restrict__ eh) {
    const int i8 = (blockIdx.x * 256 + threadIdx.x) * 8;
    const f32x4 a = *(const f32x4*)(cb + i8);
    const f32x4 b = *(const f32x4*)(cb + i8 + 4);
    short8 v;
    v[0]=bf16rne(a[0]); v[1]=bf16rne(a[1]); v[2]=bf16rne(a[2]); v[3]=bf16rne(a[3]);
    v[4]=bf16rne(b[0]); v[5]=bf16rne(b[1]); v[6]=bf16rne(b[2]); v[7]=bf16rne(b[3]);
    *(short8*)(eh + i8) = v;
}

// ---------------------------------------------------------------------------
// z [b][k][hw] fp32 -> zh [p][k] bf16 (transpose via LDS)
// ---------------------------------------------------------------------------
__global__ void vq_zh(const float* __restrict__ z, short* __restrict__ zh) {
    __shared__ float ts[64][65];
    const int b   = blockIdx.z;
    const int k0  = blockIdx.y * 64;
    const int hw0 = blockIdx.x * 64;
    const int tid = threadIdx.x;
    const int pl  = tid & 63, kk = tid >> 6;
    #pragma unroll
    for (int i = 0; i < 16; ++i) {
        const int k = kk + 4 * i;
        ts[k][pl] = z[b * BCHW + (k0 + k) * HW + hw0 + pl];
    }
    __syncthreads();
    const int tx = tid & 15, ty = tid >> 4;
    #pragma unroll
    for (int j = 0; j < 4; ++j) {
        const int p = ty + 16 * j;
        short4v v;
        #pragma unroll
        for (int q = 0; q < 4; ++q) v[q] = bf16rne(ts[tx * 4 + q][p]);
        *(short4v*)(zh + (size_t)(b * HW + hw0 + p) * KD + k0 + tx * 4) = v;
    }
}

// ---------------------------------------------------------------------------
// bf16 MFMA GEMM: s(p,n) = e2[n]/2 - <zh_p, eh_n>   (acc seeded -e2/2, s=-acc)
// 128x128 tile, BK=64, 4 waves (2x2), 16x16x32 MFMA, swizzled LDS (T2 rule #21)
// MODE 0: per-pixel global argmin via atomicMin (packed key|idx)
// MODE 1: append all (p,n) with s <= thresh[p] to candidate list
// ---------------------------------------------------------------------------
template<int MODE>
__global__ __launch_bounds__(256) void vq_gemm(
    const short* __restrict__ zh, const short* __restrict__ eh,
    const float* __restrict__ e2, u64* __restrict__ best,
    const float* __restrict__ thresh, u32* __restrict__ cand,
    u32* __restrict__ ncand, u32* __restrict__ pcount)
{
    __shared__ char As[16384];
    __shared__ char Bs[16384];
    __shared__ u64 sbest[128];

    const int tid  = threadIdx.x;
    const int lane = tid & 63;
    const int w    = tid >> 6;
    const int wm   = w >> 1, wn = w & 1;
    const int n0   = blockIdx.x * 128;
    const int p0   = blockIdx.y * 128;

    // seed acc with -e2/2 (so final s = -acc = e2/2 - dot)
    f32x4 acc[4][4];
    #pragma unroll
    for (int nf = 0; nf < 4; ++nf) {
        const float c0 = -0.5f * e2[n0 + wn * 64 + nf * 16 + (lane & 15)];
        #pragma unroll
        for (int m = 0; m < 4; ++m) acc[m][nf] = (f32x4){c0, c0, c0, c0};
    }

    const int r_in = lane >> 3;   // row within 8-row group
    const int s_in = lane & 7;    // 16B slot within 128B row

    for (int t = 0; t < 4; ++t) {
        const int k0 = t * 64;
        if (t) __syncthreads();
        // stage A (pixels) and B (codes): linear LDS dest, pre-swizzled source
        #pragma unroll
        for (int i = 0; i < 4; ++i) {
            const int r  = w * 32 + i * 8 + r_in;
            const int ss = s_in ^ (r & 7);
            GLDS((const char*)(zh + (size_t)(p0 + r) * KD + k0) + ss * 16,
                 As + (w * 32 + i * 8) * 128);
            GLDS((const char*)(eh + (size_t)(n0 + r) * KD + k0) + ss * 16,
                 Bs + (w * 32 + i * 8) * 128);
        }
        __syncthreads();
        #pragma unroll
        for (int ks = 0; ks < 2; ++ks) {
            short8 af[4], bfr[4];
            #pragma unroll
            for (int m = 0; m < 4; ++m) {
                const int row  = wm * 64 + m * 16 + (lane & 15);
                const int slot = (ks * 4 + (lane >> 4)) ^ (row & 7);
                af[m] = *(const short8*)(As + row * 128 + slot * 16);
            }
            #pragma unroll
            for (int nf = 0; nf < 4; ++nf) {
                const int row  = wn * 64 + nf * 16 + (lane & 15);
                const int slot = (ks * 4 + (lane >> 4)) ^ (row & 7);
                bfr[nf] = *(const short8*)(Bs + row * 128 + slot * 16);
            }
            #pragma unroll
            for (int m = 0; m < 4; ++m)
                #pragma unroll
                for (int nf = 0; nf < 4; ++nf)
                    acc[m][nf] = __builtin_amdgcn_mfma_f32_16x16x32_bf16(
                        af[m], bfr[nf], acc[m][nf], 0, 0, 0);
        }
    }

    if (MODE == 0) {
        if (tid < 128) sbest[tid] = ~0ULL;
        __syncthreads();
        #pragma unroll
        for (int m = 0; m < 4; ++m) {
            #pragma unroll
            for (int r = 0; r < 4; ++r) {
                float d = -acc[m][0][r];
                int  bi = n0 + wn * 64 + (lane & 15);
                #pragma unroll
                for (int nf = 1; nf < 4; ++nf) {
                    const float v  = -acc[m][nf][r];
                    const int   vn = n0 + wn * 64 + nf * 16 + (lane & 15);
                    if (v < d) { d = v; bi = vn; }
                }
                #pragma unroll
                for (int msk = 1; msk < 16; msk <<= 1) {
                    const float od = __shfl_xor(d, msk);
                    const int   oi = __shfl_xor(bi, msk);
                    if (od < d || (od == d && oi < bi)) { d = od; bi = oi; }
                }
                if ((lane & 15) == 0) {
                    const int lrow = wm * 64 + m * 16 + (lane >> 4) * 4 + r;
                    atomicMin(&sbest[lrow], ((u64)fkey(d) << 32) | (u32)bi);
                }
            }
        }
        __syncthreads();
        if (tid < 128) atomicMin(&best[p0 + tid], sbest[tid]);
    } else {
        #pragma unroll
        for (int m = 0; m < 4; ++m) {
            #pragma unroll
            for (int r = 0; r < 4; ++r) {
                const int prow = p0 + wm * 64 + m * 16 + (lane >> 4) * 4 + r;
                const float th = thresh[prow];
                #pragma unroll
                for (int nf = 0; nf < 4; ++nf) {
                    const float v = -acc[m][nf][r];
                    if (v <= th) {
                        const u32 nn  = (u32)(n0 + wn * 64 + nf * 16 + (lane & 15));
                        const u32 pos = atomicAdd(ncand, 1u);
                        if (pos < CAND_MAX) {
                            cand[pos] = ((u32)prow << 13) | nn;
                            atomicAdd(&pcount[prow], 1u);
                        }
                    }
                }
            }
        }
    }
}

// ---------------------------------------------------------------------------
__global__ void vq_thresh(const u64* __restrict__ best, float* __restrict__ thresh) {
    const int p = blockIdx.x * 256 + threadIdx.x;
    thresh[p] = unfkey((u32)(best[p] >> 32)) + DELTA;
}

// ---------------------------------------------------------------------------
// exact fp32 rescore of candidates; single-candidate pixels skip the dot
// ---------------------------------------------------------------------------
__global__ void vq_rescore(const float* __restrict__ z, const float* __restrict__ cb,
                           const float* __restrict__ e2, const u32* __restrict__ cand,
                           const u32* __restrict__ ncand, const u32* __restrict__ pcount,
                           u64* __restrict__ final_)
{
    const int gw   = (blockIdx.x * 256 + threadIdx.x) >> 6;
    const int lane = threadIdx.x & 63;
    const int nw   = gridDim.x * 4;
    const u32 nc   = min(*ncand, (u32)CAND_MAX);
    for (u32 c = gw; c < nc; c += nw) {
        const u32 e = cand[c];
        const int p = e >> 13, n = e & 8191;
        if (pcount[p] == 1u) {
            if (lane == 0) atomicMin(&final_[p], (u64)(u32)n);  // key 0 always wins
            continue;
        }
        const int bb = p >> 10, hw = p & 1023;
        const float* zp = z + bb * BCHW + hw;
        const f32x4 ev = *(const f32x4*)(cb + (size_t)n * KD + lane * 4);
        float part = zp[(lane * 4 + 0) * HW] * ev[0] + zp[(lane * 4 + 1) * HW] * ev[1]
                   + zp[(lane * 4 + 2) * HW] * ev[2] + zp[(lane * 4 + 3) * HW] * ev[3];
        #pragma unroll
        for (int m = 1; m < 64; m <<= 1) part += __shfl_xor(part, m);
        if (lane == 0) {
            const float s = 0.5f * e2[n] - part;
            atomicMin(&final_[p], ((u64)fkey(s) << 32) | (u32)n);
        }
    }
}

// ---------------------------------------------------------------------------
__global__ void vq_idx(const u64* __restrict__ final_, float* __restrict__ idxf) {
    const int p = blockIdx.x * 256 + threadIdx.x;
    idxf[p] = (float)(u32)(final_[p] & 0xFFFFFFFFull);
}

// ---------------------------------------------------------------------------
// z_q gather (channel-first) + loss = 1.25*mean((z_q - z)^2)
// ---------------------------------------------------------------------------
__global__ void vq_out_kernel(const float* __restrict__ z, const float* __restrict__ cb,
                              const float* __restrict__ idxf, float* __restrict__ out,
                              float* __restrict__ loss)
{
    const int e  = (blockIdx.x * 256 + threadIdx.x) * 4;
    const int bb = e >> 18;
    const int c  = (e >> 10) & 255;
    const int hw = e & 1023;
    const int p  = bb * HW + hw;

    const float4 zv = *reinterpret_cast<const float4*>(z + e);
    const float zl[4] = {zv.x, zv.y, zv.z, zv.w};
    float o[4];
    float ls = 0.f;
    #pragma unroll
    for (int i = 0; i < 4; ++i) {
        const int n = (int)idxf[p + i];
        o[i] = cb[(size_t)n * KD + c];
        const float dd = o[i] - zl[i];
        ls += dd * dd;
    }
    const float4 ov = {o[0], o[1], o[2], o[3]};
    *reinterpret_cast<float4*>(out + e) = ov;

    #pragma unroll
    for (int m = 1; m < 64; m <<= 1) ls += __shfl_xor(ls, m);
    if ((threadIdx.x & 63) == 0) atomicAdd(loss, ls * (1.25f / 4194304.f));
}

// ---------------------------------------------------------------------------
extern "C" void kernel_launch(void* const* d_in, const int* in_sizes, int n_in,
                              void* d_out, int out_size, void* d_ws, size_t ws_size,
                              hipStream_t stream) {
    const float* z  = (const float*)d_in[0];
    const float* cb = (const float*)d_in[1];
    float* out  = (float*)d_out;            // [0 .. 4194303] z_q (used as bf16 scratch first)
    float* idxf = out + 4194304;            // index as float
    float* loss = out + 4210688;            // loss scalar
    short* zh = (short*)out;                // 8 MB bf16 z transposed [p][k]
    short* eh = (short*)(out + 2097152);    // 4 MB bf16 codebook

    char* ws = (char*)d_ws;
    u64*   best   = (u64*)ws;               // 128 KB
    u64*   final_ = (u64*)(ws + 131072);    // 128 KB
    float* thresh = (float*)(ws + 262144);  // 64 KB
    float* e2     = (float*)(ws + 327680);  // 32 KB
    u32*   pcount = (u32*)(ws + 360448);    // 64 KB
    u32*   cand   = (u32*)(ws + 425984);    // 256 KB
    u32*   ncand  = (u32*)(ws + 688128);    // 4 B

    hipMemsetAsync(best,   0xFF, 131072, stream);
    hipMemsetAsync(final_, 0xFF, 131072, stream);
    hipMemsetAsync(pcount, 0,    65536,  stream);
    hipMemsetAsync(ncand,  0,    4,      stream);
    hipMemsetAsync(loss,   0,    4,      stream);

    vq_e2_kernel<<<2048, 256, 0, stream>>>(cb, e2);
    vq_eh<<<1024, 256, 0, stream>>>(cb, eh);
    vq_zh<<<dim3(16, 4, 16), 256, 0, stream>>>(z, zh);
    vq_gemm<0><<<dim3(64, 128), 256, 0, stream>>>(zh, eh, e2, best, thresh, cand, ncand, pcount);
    vq_thresh<<<64, 256, 0, stream>>>(best, thresh);
    vq_gemm<1><<<dim3(64, 128), 256, 0, stream>>>(zh, eh, e2, best, thresh, cand, ncand, pcount);
    vq_rescore<<<64, 256, 0, stream>>>(z, cb, e2, cand, ncand, pcount, final_);
    vq_idx<<<64, 256, 0, stream>>>(final_, idxf);
    vq_out_kernel<<<4096, 256, 0, stream>>>(z, cb, idxf, out, loss);
}